// Round 1
// baseline (765.778 us; speedup 1.0000x reference)
//
#include <hip/hip_runtime.h>

#define NB 4
#define NN 10000
#define NE 320000
#define EPB 64
#define NBLK ((NB * NE) / EPB)   // 20000

typedef unsigned int uint;
typedef unsigned short ushort;
typedef __attribute__((ext_vector_type(8))) short short8;
typedef __attribute__((ext_vector_type(4))) float f32x4;

// d_ws layout (bytes)
#define WS_W2  0        // 2048 frags * 16B = 32768
#define WS_W3  32768
#define WS_W1P 65536    // 128 rows * 8 f32 (w0..w5, b1, pad) = 4096
#define WS_WV  69632    // 64 rows * 8 f32 (Wv/3, pad) = 2048

static __device__ __forceinline__ ushort f2bf(float f) {
    uint u = __float_as_uint(f);
    u += 0x7fffu + ((u >> 16) & 1u);
    return (ushort)(u >> 16);
}
static __device__ __forceinline__ short8 u4s8(uint4 v) {
    union { uint4 u; short8 s; } x; x.u = v; return x.s;
}

// ---------------- prep: pack weights ----------------
// B-frag convention (same for A-side in main kernel): frag(wn,ct,kt), lane l:
//   col = wn*64 + ct*16 + (l&15); elem j -> k = kt*32 + (j>>2)*16 + (l>>4)*4 + (j&3)
__global__ void prep_kernel(const float* __restrict__ W1, const float* __restrict__ b1,
                            const float* __restrict__ W2, const float* __restrict__ W3,
                            const float* __restrict__ Wv, unsigned char* __restrict__ ws) {
    int tid = blockIdx.x * blockDim.x + threadIdx.x;
    if (tid < 4096) {
        const float* W = (tid < 2048) ? W2 : W3;
        uint4* dst = (uint4*)(ws + ((tid < 2048) ? WS_W2 : WS_W3));
        int f = tid & 2047;
        int lane = f & 63, kt = (f >> 6) & 3, ct = (f >> 8) & 3, wn = (f >> 10) & 1;
        int a = lane >> 4, lm = lane & 15;
        int col = wn * 64 + ct * 16 + lm;
        uint w[4];
        #pragma unroll
        for (int jw = 0; jw < 4; ++jw) {
            int j0 = jw * 2, j1 = j0 + 1;
            int k0 = kt * 32 + (j0 >> 2) * 16 + a * 4 + (j0 & 3);
            int k1 = kt * 32 + (j1 >> 2) * 16 + a * 4 + (j1 & 3);
            w[jw] = (uint)f2bf(W[col * 128 + k0]) | ((uint)f2bf(W[col * 128 + k1]) << 16);
        }
        dst[f] = make_uint4(w[0], w[1], w[2], w[3]);
    } else if (tid < 5120) {
        int s = tid - 4096;
        int c = s >> 3, i = s & 7;
        float v = (i < 6) ? W1[c * 6 + i] : ((i == 6) ? b1[c] : 0.f);
        ((float*)(ws + WS_W1P))[s] = v;
    } else if (tid < 5632) {
        int s = tid - 5120;
        int o = s >> 3, i = s & 7;
        float v = (i < 6) ? Wv[o * 6 + i] * (1.f / 3.f) : 0.f;
        ((float*)(ws + WS_WV))[s] = v;
    }
}

// ---------------- main ----------------
__global__ __launch_bounds__(256, 2)
void edge_kernel(const float* __restrict__ pos0, const float* __restrict__ pos1,
                 const int* __restrict__ src, const int* __restrict__ dstI,
                 const float* __restrict__ b2, const float* __restrict__ b3,
                 const unsigned char* __restrict__ ws, float* __restrict__ out) {
    __shared__ float s_pts[64][13];
    __shared__ float s_norms[64][8];
    __shared__ float s_vecs[64][21];
    __shared__ float s_W1p[1024];   // [128][8] f32, XOR-swizzled by ((c>>2)&3)<<2 dwords
    __shared__ float s_Wv[512];     // [64][8] f32, XOR-swizzled by ((o>>4)&3)<<2 dwords
    __shared__ uint4 s_H2[1024];    // frag-major H2: (kt*4+mt)*64 + laneSlot

    const int tid = threadIdx.x;
    const int lane = tid & 63;
    const int wid = tid >> 6;
    const int wm = wid >> 1;        // M-half: rows [wm*32, wm*32+32)
    const int wn = wid & 1;         // N-half: cols [wn*64, wn*64+64)
    const int lm = lane & 15;
    const int la = lane >> 4;

    const int bid = blockIdx.x;
    const int b = bid / (NE / EPB);
    const int e0 = (bid % (NE / EPB)) * EPB;

    // --- W2/W3 B-fragments into registers (from L2-resident ws) ---
    uint4 w2f[4][4], w3f[4][4];
    const uint4* W2F = (const uint4*)(ws + WS_W2);
    const uint4* W3F = (const uint4*)(ws + WS_W3);
    #pragma unroll
    for (int ct = 0; ct < 4; ++ct)
        #pragma unroll
        for (int kt = 0; kt < 4; ++kt) {
            int idx = ((wn * 4 + ct) * 4 + kt) * 64 + lane;
            w2f[ct][kt] = W2F[idx];
            w3f[ct][kt] = W3F[idx];
        }
    float b2c[4], b3c[4];
    #pragma unroll
    for (int ct = 0; ct < 4; ++ct) {
        int col = wn * 64 + ct * 16 + lm;
        b2c[ct] = b2[col];
        b3c[ct] = b3[col];
    }

    // --- phase A: gather endpoint positions + stage W1p/Wv into LDS ---
    {
        int le = tid & 63;
        int pt = tid >> 6;                       // 0:p0s 1:p0d 2:p1s 3:p1d
        int e = e0 + le;
        int node = (pt & 1) ? dstI[e] : src[e];
        const float* P = (pt < 2) ? pos0 : pos1;
        const float* p = P + ((size_t)b * NN + node) * 3;
        s_pts[le][pt * 3 + 0] = p[0];
        s_pts[le][pt * 3 + 1] = p[1];
        s_pts[le][pt * 3 + 2] = p[2];
        int d0 = tid * 4;
        *(uint4*)&s_W1p[d0 ^ (((d0 >> 5) & 3) << 2)] = ((const uint4*)(ws + WS_W1P))[tid];
        if (tid < 128) {
            int d1 = tid * 4;
            *(uint4*)&s_Wv[d1 ^ (((d1 >> 7) & 3) << 2)] = ((const uint4*)(ws + WS_WV))[tid];
        }
    }
    __syncthreads();

    // --- phase B: vecs + norms (wave 0) ---
    if (tid < 64) {
        float P[12];
        #pragma unroll
        for (int i = 0; i < 12; ++i) P[i] = s_pts[tid][i];
        const int va[6] = {1, 3, 2, 3, 2, 3};
        const int vb[6] = {0, 2, 0, 1, 1, 0};
        #pragma unroll
        for (int i = 0; i < 6; ++i) {
            float x = P[va[i] * 3 + 0] - P[vb[i] * 3 + 0];
            float y = P[va[i] * 3 + 1] - P[vb[i] * 3 + 1];
            float z = P[va[i] * 3 + 2] - P[vb[i] * 3 + 2];
            s_vecs[tid][i * 3 + 0] = x;
            s_vecs[tid][i * 3 + 1] = y;
            s_vecs[tid][i * 3 + 2] = z;
            s_norms[tid][i] = sqrtf(x * x + y * y + z * z);
        }
    }
    __syncthreads();

    // --- layer 1 (fp32 VALU) directly into A-fragment registers ---
    float nm[2][6];
    #pragma unroll
    for (int mtl = 0; mtl < 2; ++mtl) {
        int row = wm * 32 + mtl * 16 + lm;
        #pragma unroll
        for (int i = 0; i < 6; ++i) nm[mtl][i] = s_norms[row][i];
    }
    uint4 af[2][4];
    #pragma unroll
    for (int kt = 0; kt < 4; ++kt) {
        uint w0[4], w1[4];
        #pragma unroll
        for (int jw = 0; jw < 4; ++jw) {
            ushort u0[2], u1[2];
            #pragma unroll
            for (int dc = 0; dc < 2; ++dc) {
                int j = jw * 2 + dc;
                int c = kt * 32 + (j >> 2) * 16 + la * 4 + (j & 3);
                int sw = ((c >> 2) & 3) << 2;
                const float4 lo = *(const float4*)&s_W1p[(c * 8) ^ sw];
                const float4 hi = *(const float4*)&s_W1p[(c * 8 + 4) ^ sw];
                #pragma unroll
                for (int mtl = 0; mtl < 2; ++mtl) {
                    float acc = hi.z;                       // b1[c]
                    acc = fmaf(nm[mtl][0], lo.x, acc);
                    acc = fmaf(nm[mtl][1], lo.y, acc);
                    acc = fmaf(nm[mtl][2], lo.z, acc);
                    acc = fmaf(nm[mtl][3], lo.w, acc);
                    acc = fmaf(nm[mtl][4], hi.x, acc);
                    acc = fmaf(nm[mtl][5], hi.y, acc);
                    acc = (acc >= 0.f) ? acc : 0.2f * acc;
                    ushort r = f2bf(acc);
                    if (mtl == 0) u0[dc] = r; else u1[dc] = r;
                }
            }
            w0[jw] = (uint)u0[0] | ((uint)u0[1] << 16);
            w1[jw] = (uint)u1[0] | ((uint)u1[1] << 16);
        }
        af[0][kt] = make_uint4(w0[0], w0[1], w0[2], w0[3]);
        af[1][kt] = make_uint4(w1[0], w1[1], w1[2], w1[3]);
    }

    // --- layer 2 MFMA ---
    const f32x4 zero4 = {0.f, 0.f, 0.f, 0.f};
    f32x4 acc2[2][4];
    #pragma unroll
    for (int mtl = 0; mtl < 2; ++mtl)
        #pragma unroll
        for (int ct = 0; ct < 4; ++ct) acc2[mtl][ct] = zero4;
    #pragma unroll
    for (int kt = 0; kt < 4; ++kt)
        #pragma unroll
        for (int ct = 0; ct < 4; ++ct)
            #pragma unroll
            for (int mtl = 0; mtl < 2; ++mtl)
                acc2[mtl][ct] = __builtin_amdgcn_mfma_f32_16x16x32_bf16(
                    u4s8(af[mtl][kt]), u4s8(w2f[ct][kt]), acc2[mtl][ct], 0, 0, 0);

    // --- epilogue L2: bias + leaky + bf16 -> frag-major H2 in LDS ---
    #pragma unroll
    for (int mtl = 0; mtl < 2; ++mtl) {
        const int mt = wm * 2 + mtl;
        #pragma unroll
        for (int ct = 0; ct < 4; ++ct) {
            const int colg = wn * 64 + ct * 16 + lm;
            const int kt3 = colg >> 5;
            const int c32 = colg & 31;
            const int slot = ((c32 & 15) >> 2) * 16;
            const int j = (c32 & 3) + ((c32 >> 4) << 2);
            const float bb = b2c[ct];
            #pragma unroll
            for (int r = 0; r < 4; ++r) {
                float v = acc2[mtl][ct][r] + bb;
                v = (v >= 0.f) ? v : 0.2f * v;
                ushort* p = (ushort*)&s_H2[(kt3 * 4 + mt) * 64 + slot + (la * 4 + r)];
                p[j] = f2bf(v);
            }
        }
    }
    __syncthreads();

    // --- layer 3 MFMA (A from H2) ---
    #pragma unroll
    for (int mtl = 0; mtl < 2; ++mtl)
        #pragma unroll
        for (int kt = 0; kt < 4; ++kt)
            af[mtl][kt] = s_H2[(kt * 4 + wm * 2 + mtl) * 64 + lane];
    f32x4 acc3[2][4];
    #pragma unroll
    for (int mtl = 0; mtl < 2; ++mtl)
        #pragma unroll
        for (int ct = 0; ct < 4; ++ct) acc3[mtl][ct] = zero4;
    #pragma unroll
    for (int kt = 0; kt < 4; ++kt)
        #pragma unroll
        for (int ct = 0; ct < 4; ++ct)
            #pragma unroll
            for (int mtl = 0; mtl < 2; ++mtl)
                acc3[mtl][ct] = __builtin_amdgcn_mfma_f32_16x16x32_bf16(
                    u4s8(af[mtl][kt]), u4s8(w3f[ct][kt]), acc3[mtl][ct], 0, 0, 0);

    // --- store a_out (fp32) ---
    const size_t aBase = (size_t)b * NE + e0;
    #pragma unroll
    for (int mtl = 0; mtl < 2; ++mtl)
        #pragma unroll
        for (int ct = 0; ct < 4; ++ct) {
            const int colg = wn * 64 + ct * 16 + lm;
            #pragma unroll
            for (int r = 0; r < 4; ++r) {
                int row = wm * 32 + mtl * 16 + la * 4 + r;
                out[(aBase + row) * 128 + colg] = acc3[mtl][ct][r] + b3c[ct];
            }
        }

    // --- v_out (fp32, exact) ---
    {
        const int le = tid >> 2;
        const int q = tid & 3;
        float vv[18];
        #pragma unroll
        for (int i = 0; i < 18; ++i) vv[i] = s_vecs[le][i];
        float* vout = out + (size_t)NB * NE * 128 + ((size_t)b * NE + e0 + le) * 192 + q * 48;
        #pragma unroll
        for (int og = 0; og < 4; ++og) {
            float buf[12];
            #pragma unroll
            for (int oo = 0; oo < 4; ++oo) {
                int o = q * 16 + og * 4 + oo;
                int sw = ((o >> 4) & 3) << 2;
                const float4 wlo = *(const float4*)&s_Wv[(o * 8) ^ sw];
                const float4 whi = *(const float4*)&s_Wv[(o * 8 + 4) ^ sw];
                #pragma unroll
                for (int k = 0; k < 3; ++k) {
                    float r = wlo.x * vv[0 + k];
                    r = fmaf(wlo.y, vv[3 + k], r);
                    r = fmaf(wlo.z, vv[6 + k], r);
                    r = fmaf(wlo.w, vv[9 + k], r);
                    r = fmaf(whi.x, vv[12 + k], r);
                    r = fmaf(whi.y, vv[15 + k], r);
                    buf[oo * 3 + k] = r;
                }
            }
            #pragma unroll
            for (int v4 = 0; v4 < 3; ++v4)
                *(float4*)&vout[og * 12 + v4 * 4] = *(float4*)&buf[v4 * 4];
        }
    }
}

extern "C" void kernel_launch(void* const* d_in, const int* in_sizes, int n_in,
                              void* d_out, int out_size, void* d_ws, size_t ws_size,
                              hipStream_t stream) {
    const float* pos0 = (const float*)d_in[0];
    const float* pos1 = (const float*)d_in[1];
    const int* src = (const int*)d_in[2];
    const int* dstI = (const int*)d_in[3];
    const float* Wv = (const float*)d_in[4];
    const float* W1 = (const float*)d_in[5];
    const float* b1 = (const float*)d_in[6];
    const float* W2 = (const float*)d_in[7];
    const float* b2 = (const float*)d_in[8];
    const float* W3 = (const float*)d_in[9];
    const float* b3 = (const float*)d_in[10];
    unsigned char* ws = (unsigned char*)d_ws;
    float* out = (float*)d_out;

    prep_kernel<<<dim3(22), dim3(256), 0, stream>>>(W1, b1, W2, W3, Wv, ws);
    edge_kernel<<<dim3(NBLK), dim3(256), 0, stream>>>(pos0, pos1, src, dstI, b2, b3, ws, out);
}

// Round 2
// 472.685 us; speedup vs baseline: 1.6201x; 1.6201x over previous
//
#include <hip/hip_runtime.h>

#define NB 4
#define NN 10000
#define NE 320000
#define EPB 64
#define NBLK ((NB * NE) / EPB)   // 20000

typedef unsigned int uint;
typedef unsigned short ushort;
typedef __attribute__((ext_vector_type(8))) short short8;
typedef __attribute__((ext_vector_type(4))) float f32x4;

// d_ws layout (bytes)
#define WS_W2F 0        // 2048 frags * 16B
#define WS_W3F 32768    // 2048 frags * 16B
#define WS_W1F 65536    // 512 frags * 16B
#define WS_WV  73728    // 64 rows * 8 f32 (Wv/3, pad)

static __device__ __forceinline__ ushort f2bf(float f) {
    uint u = __float_as_uint(f);
    u += 0x7fffu + ((u >> 16) & 1u);
    return (ushort)(u >> 16);
}
static __device__ __forceinline__ uint pack2(float a, float b) {
    return (uint)f2bf(a) | ((uint)f2bf(b) << 16);
}
static __device__ __forceinline__ short8 u4s8(uint4 v) {
    union { uint4 u; short8 s; } x; x.u = v; return x.s;
}
static __device__ __forceinline__ float lk(float x) { return x >= 0.f ? x : 0.2f * x; }

// ---------------- prep: pack weights ----------------
// Frag convention (A and B identical): frag(ct,kt), lane l (la=l>>4, lm=l&15):
//   col/row16 = ct*16 + lm; elem j -> k = kt*32 + (j>>2)*16 + la*4 + (j&3)
__global__ void prep_kernel(const float* __restrict__ W1, const float* __restrict__ W2,
                            const float* __restrict__ W3, const float* __restrict__ Wv,
                            unsigned char* __restrict__ ws) {
    int tid = blockIdx.x * blockDim.x + threadIdx.x;
    if (tid < 4096) {
        const float* W = (tid < 2048) ? W2 : W3;
        uint4* dst = (uint4*)(ws + ((tid < 2048) ? WS_W2F : WS_W3F));
        int f = tid & 2047;
        int lane = f & 63, kt = (f >> 6) & 3, ct = (f >> 8) & 3, wn = (f >> 10) & 1;
        int a = lane >> 4, lm = lane & 15;
        int col = wn * 64 + ct * 16 + lm;
        uint w[4];
        #pragma unroll
        for (int jw = 0; jw < 4; ++jw) {
            int j0 = jw * 2, j1 = j0 + 1;
            int k0 = kt * 32 + (j0 >> 2) * 16 + a * 4 + (j0 & 3);
            int k1 = kt * 32 + (j1 >> 2) * 16 + a * 4 + (j1 & 3);
            w[jw] = pack2(W[col * 128 + k0], W[col * 128 + k1]);
        }
        dst[f] = make_uint4(w[0], w[1], w[2], w[3]);
    } else if (tid < 4608) {
        int f = tid - 4096;          // 512 frag slots: (wn,ct,lane), kt=0
        int lane = f & 63, ct = (f >> 6) & 3, wn = (f >> 8) & 1;
        int a = lane >> 4, lm = lane & 15;
        int col = wn * 64 + ct * 16 + lm;
        uint w[4];
        #pragma unroll
        for (int jw = 0; jw < 4; ++jw) {
            int j0 = jw * 2, j1 = j0 + 1;
            int k0 = (j0 >> 2) * 16 + a * 4 + (j0 & 3);
            int k1 = (j1 >> 2) * 16 + a * 4 + (j1 & 3);
            float f0 = (k0 < 6) ? W1[col * 6 + k0] : 0.f;
            float f1 = (k1 < 6) ? W1[col * 6 + k1] : 0.f;
            w[jw] = pack2(f0, f1);
        }
        ((uint4*)(ws + WS_W1F))[f] = make_uint4(w[0], w[1], w[2], w[3]);
    } else if (tid < 5120) {
        int s = tid - 4608;
        int o = s >> 3, i = s & 7;
        ((float*)(ws + WS_WV))[s] = (i < 6) ? Wv[o * 6 + i] * (1.f / 3.f) : 0.f;
    }
}

// ---------------- main ----------------
__global__ __launch_bounds__(256, 2)
void edge_kernel(const float* __restrict__ pos0, const float* __restrict__ pos1,
                 const int* __restrict__ src, const int* __restrict__ dstI,
                 const float* __restrict__ b1, const float* __restrict__ b2,
                 const float* __restrict__ b3,
                 const unsigned char* __restrict__ ws, float* __restrict__ out) {
    __shared__ float s_pts[64][13];
    __shared__ float s_vecs[64][28];
    __shared__ uint4 s_H1[256];       // bf16 A-frags of norms: [mt][lane]
    __shared__ float s_hf[64 * 128];  // f32 h-buffer (XOR-swizzled); reused h1->h2->a_out->v_stage

    const int tid = threadIdx.x;
    const int lane = tid & 63;
    const int wid = tid >> 6;
    const int wm = wid >> 1;          // M-half: rows [wm*32, wm*32+32)
    const int wn = wid & 1;           // N-half: cols [wn*64, wn*64+64)
    const int lm = lane & 15;
    const int la = lane >> 4;

    const int bid = blockIdx.x;
    const int b = bid / (NE / EPB);
    const int e0 = (bid % (NE / EPB)) * EPB;

    // --- weight fragments into registers (L2-resident ws) ---
    const uint4* W1F = (const uint4*)(ws + WS_W1F);
    const uint4* W2F = (const uint4*)(ws + WS_W2F);
    const uint4* W3F = (const uint4*)(ws + WS_W3F);
    uint4 w1f[4], w2f[4][4], w3f[4][4];
    #pragma unroll
    for (int ct = 0; ct < 4; ++ct) w1f[ct] = W1F[(wn * 4 + ct) * 64 + lane];
    #pragma unroll
    for (int ct = 0; ct < 4; ++ct)
        #pragma unroll
        for (int kt = 0; kt < 4; ++kt) {
            int idx = ((wn * 4 + ct) * 4 + kt) * 64 + lane;
            w2f[ct][kt] = W2F[idx];
            w3f[ct][kt] = W3F[idx];
        }
    float b1c[4], b2c[4], b3c[4];
    #pragma unroll
    for (int ct = 0; ct < 4; ++ct) {
        int col = wn * 64 + ct * 16 + lm;
        b1c[ct] = b1[col];
        b2c[ct] = b2[col];
        b3c[ct] = b3[col];
    }

    // --- phase A: gather endpoint positions ---
    {
        int le = tid & 63;
        int pt = tid >> 6;                       // 0:p0s 1:p0d 2:p1s 3:p1d
        int e = e0 + le;
        int node = (pt & 1) ? dstI[e] : src[e];
        const float* P = (pt < 2) ? pos0 : pos1;
        const float* p = P + ((size_t)b * NN + node) * 3;
        s_pts[le][pt * 3 + 0] = p[0];
        s_pts[le][pt * 3 + 1] = p[1];
        s_pts[le][pt * 3 + 2] = p[2];
    }
    __syncthreads();

    // --- phase B: vecs + norm A-frags (wave w handles la=w slots) ---
    {
        const int row = tid & 63;
        const int w = tid >> 6;
        uint4 hf = make_uint4(0, 0, 0, 0);
        if (w == 0) {
            float P[12];
            #pragma unroll
            for (int i = 0; i < 12; ++i) P[i] = s_pts[row][i];
            // vecs 0..3: (1,0) (3,2) (2,0) (3,1)
            const int va[4] = {1, 3, 2, 3}, vb[4] = {0, 2, 0, 1};
            float v[4][3], n[4];
            #pragma unroll
            for (int i = 0; i < 4; ++i) {
                #pragma unroll
                for (int c = 0; c < 3; ++c) v[i][c] = P[va[i] * 3 + c] - P[vb[i] * 3 + c];
                n[i] = sqrtf(v[i][0] * v[i][0] + v[i][1] * v[i][1] + v[i][2] * v[i][2]);
            }
            float4 t0 = {v[0][0], v[0][1], v[0][2], v[1][0]};
            float4 t1 = {v[1][1], v[1][2], v[2][0], v[2][1]};
            float4 t2 = {v[2][2], v[3][0], v[3][1], v[3][2]};
            *(float4*)&s_vecs[row][0] = t0;
            *(float4*)&s_vecs[row][4] = t1;
            *(float4*)&s_vecs[row][8] = t2;
            hf.x = pack2(n[0], n[1]);
            hf.y = pack2(n[2], n[3]);
        } else if (w == 1) {
            float P[12];
            #pragma unroll
            for (int i = 0; i < 12; ++i) P[i] = s_pts[row][i];
            float v4[3], v5[3];
            #pragma unroll
            for (int c = 0; c < 3; ++c) {
                v4[c] = P[6 + c] - P[3 + c];   // p1s - p0d
                v5[c] = P[9 + c] - P[0 + c];   // p1d - p0s
            }
            float n4 = sqrtf(v4[0] * v4[0] + v4[1] * v4[1] + v4[2] * v4[2]);
            float n5 = sqrtf(v5[0] * v5[0] + v5[1] * v5[1] + v5[2] * v5[2]);
            float4 t = {v4[0], v4[1], v4[2], v5[0]};
            *(float4*)&s_vecs[row][12] = t;
            float2 t2 = {v5[1], v5[2]};
            *(float2*)&s_vecs[row][16] = t2;
            hf.x = pack2(n4, n5);
        }
        s_H1[(row >> 4) * 64 + w * 16 + (row & 15)] = hf;
    }
    __syncthreads();

    // --- layer 1 MFMA ---
    const f32x4 zero4 = {0.f, 0.f, 0.f, 0.f};
    short8 afh[2];
    afh[0] = u4s8(s_H1[(wm * 2 + 0) * 64 + lane]);
    afh[1] = u4s8(s_H1[(wm * 2 + 1) * 64 + lane]);
    f32x4 acc1[2][4];
    #pragma unroll
    for (int mtl = 0; mtl < 2; ++mtl)
        #pragma unroll
        for (int ct = 0; ct < 4; ++ct) {
            acc1[mtl][ct] = __builtin_amdgcn_mfma_f32_16x16x32_bf16(
                afh[mtl], u4s8(w1f[ct]), zero4, 0, 0, 0);
        }
    // epilogue L1: bias + leaky -> f32 swizzled h-buffer
    #pragma unroll
    for (int mtl = 0; mtl < 2; ++mtl)
        #pragma unroll
        for (int ct = 0; ct < 4; ++ct) {
            const int col = wn * 64 + ct * 16 + lm;
            #pragma unroll
            for (int r = 0; r < 4; ++r) {
                int row = wm * 32 + mtl * 16 + la * 4 + r;
                s_hf[row * 128 + (col ^ ((row & 7) << 2))] = lk(acc1[mtl][ct][r] + b1c[ct]);
            }
        }
    __syncthreads();

    // --- build A-frags for L2 (contiguous b128 reads + cvt) ---
    const int swR = (lm & 7) << 2;
    uint4 af2[2][4];
    #pragma unroll
    for (int mtl = 0; mtl < 2; ++mtl) {
        const int row = wm * 32 + mtl * 16 + lm;
        const float* hrow = &s_hf[row * 128];
        #pragma unroll
        for (int kt = 0; kt < 4; ++kt) {
            float4 lo = *(const float4*)&hrow[(kt * 32 + la * 4) ^ swR];
            float4 hi = *(const float4*)&hrow[(kt * 32 + 16 + la * 4) ^ swR];
            af2[mtl][kt] = make_uint4(pack2(lo.x, lo.y), pack2(lo.z, lo.w),
                                      pack2(hi.x, hi.y), pack2(hi.z, hi.w));
        }
    }
    __syncthreads();   // all reads done before h2 overwrite

    // --- layer 2 MFMA ---
    f32x4 acc2[2][4];
    #pragma unroll
    for (int mtl = 0; mtl < 2; ++mtl)
        #pragma unroll
        for (int ct = 0; ct < 4; ++ct) acc2[mtl][ct] = zero4;
    #pragma unroll
    for (int kt = 0; kt < 4; ++kt)
        #pragma unroll
        for (int ct = 0; ct < 4; ++ct)
            #pragma unroll
            for (int mtl = 0; mtl < 2; ++mtl)
                acc2[mtl][ct] = __builtin_amdgcn_mfma_f32_16x16x32_bf16(
                    u4s8(af2[mtl][kt]), u4s8(w2f[ct][kt]), acc2[mtl][ct], 0, 0, 0);
    #pragma unroll
    for (int mtl = 0; mtl < 2; ++mtl)
        #pragma unroll
        for (int ct = 0; ct < 4; ++ct) {
            const int col = wn * 64 + ct * 16 + lm;
            #pragma unroll
            for (int r = 0; r < 4; ++r) {
                int row = wm * 32 + mtl * 16 + la * 4 + r;
                s_hf[row * 128 + (col ^ ((row & 7) << 2))] = lk(acc2[mtl][ct][r] + b2c[ct]);
            }
        }
    __syncthreads();

    // --- build A-frags for L3 ---
    uint4 af3[2][4];
    #pragma unroll
    for (int mtl = 0; mtl < 2; ++mtl) {
        const int row = wm * 32 + mtl * 16 + lm;
        const float* hrow = &s_hf[row * 128];
        #pragma unroll
        for (int kt = 0; kt < 4; ++kt) {
            float4 lo = *(const float4*)&hrow[(kt * 32 + la * 4) ^ swR];
            float4 hi = *(const float4*)&hrow[(kt * 32 + 16 + la * 4) ^ swR];
            af3[mtl][kt] = make_uint4(pack2(lo.x, lo.y), pack2(lo.z, lo.w),
                                      pack2(hi.x, hi.y), pack2(hi.z, hi.w));
        }
    }
    __syncthreads();

    // --- layer 3 MFMA ---
    f32x4 acc3[2][4];
    #pragma unroll
    for (int mtl = 0; mtl < 2; ++mtl)
        #pragma unroll
        for (int ct = 0; ct < 4; ++ct) acc3[mtl][ct] = zero4;
    #pragma unroll
    for (int kt = 0; kt < 4; ++kt)
        #pragma unroll
        for (int ct = 0; ct < 4; ++ct)
            #pragma unroll
            for (int mtl = 0; mtl < 2; ++mtl)
                acc3[mtl][ct] = __builtin_amdgcn_mfma_f32_16x16x32_bf16(
                    u4s8(af3[mtl][kt]), u4s8(w3f[ct][kt]), acc3[mtl][ct], 0, 0, 0);
    // a_out epilogue -> s_hf (bias only)
    #pragma unroll
    for (int mtl = 0; mtl < 2; ++mtl)
        #pragma unroll
        for (int ct = 0; ct < 4; ++ct) {
            const int col = wn * 64 + ct * 16 + lm;
            #pragma unroll
            for (int r = 0; r < 4; ++r) {
                int row = wm * 32 + mtl * 16 + la * 4 + r;
                s_hf[row * 128 + (col ^ ((row & 7) << 2))] = acc3[mtl][ct][r] + b3c[ct];
            }
        }
    __syncthreads();

    // --- a_out flat coalesced store ---
    const size_t aBase = ((size_t)b * NE + e0) * 128;
    #pragma unroll
    for (int i = 0; i < 8; ++i) {
        int f = i * 256 + tid;
        int row = f >> 5;
        int c4 = (f & 31) << 2;
        float4 v = *(const float4*)&s_hf[row * 128 + (c4 ^ ((row & 7) << 2))];
        *(float4*)&out[aBase + (size_t)f * 4] = v;
    }
    __syncthreads();

    // --- v_out: compute per (edge, 8-o segment), stage in LDS, flat store ---
    const int seg = tid & 7;
    const int eL = tid >> 3;
    float4 wvr[16];
    const float4* WVp = (const float4*)(ws + WS_WV);
    #pragma unroll
    for (int j = 0; j < 16; ++j) wvr[j] = WVp[seg * 16 + j];
    float* s_V = s_hf;   // 32 edges * 196 floats = 25.1 KB per half
    const size_t vBase = (size_t)NB * NE * 128 + ((size_t)b * NE + e0) * 192;
    #pragma unroll
    for (int h = 0; h < 2; ++h) {
        const int e = h * 32 + eL;
        float vv[18];
        {
            float4 a0 = *(const float4*)&s_vecs[e][0];
            float4 a1 = *(const float4*)&s_vecs[e][4];
            float4 a2 = *(const float4*)&s_vecs[e][8];
            float4 a3 = *(const float4*)&s_vecs[e][12];
            vv[0] = a0.x; vv[1] = a0.y; vv[2] = a0.z; vv[3] = a0.w;
            vv[4] = a1.x; vv[5] = a1.y; vv[6] = a1.z; vv[7] = a1.w;
            vv[8] = a2.x; vv[9] = a2.y; vv[10] = a2.z; vv[11] = a2.w;
            vv[12] = a3.x; vv[13] = a3.y; vv[14] = a3.z; vv[15] = a3.w;
            vv[16] = s_vecs[e][16]; vv[17] = s_vecs[e][17];
        }
        float buf[24];
        #pragma unroll
        for (int oo = 0; oo < 8; ++oo) {
            float4 wlo = wvr[oo * 2], whi = wvr[oo * 2 + 1];
            #pragma unroll
            for (int k = 0; k < 3; ++k) {
                float r = wlo.x * vv[k];
                r = fmaf(wlo.y, vv[3 + k], r);
                r = fmaf(wlo.z, vv[6 + k], r);
                r = fmaf(wlo.w, vv[9 + k], r);
                r = fmaf(whi.x, vv[12 + k], r);
                r = fmaf(whi.y, vv[15 + k], r);
                buf[oo * 3 + k] = r;
            }
        }
        #pragma unroll
        for (int w4 = 0; w4 < 6; ++w4) {
            float4 t = {buf[w4 * 4], buf[w4 * 4 + 1], buf[w4 * 4 + 2], buf[w4 * 4 + 3]};
            *(float4*)&s_V[eL * 196 + seg * 24 + w4 * 4] = t;
        }
        __syncthreads();
        #pragma unroll
        for (int i = 0; i < 6; ++i) {
            int f4 = i * 256 + tid;
            int ef = f4 / 48;
            int r4 = (f4 - ef * 48) * 4;
            float4 v = *(const float4*)&s_V[ef * 196 + r4];
            *(float4*)&out[vBase + (size_t)h * 6144 + (size_t)f4 * 4] = v;
        }
        __syncthreads();
    }
}

extern "C" void kernel_launch(void* const* d_in, const int* in_sizes, int n_in,
                              void* d_out, int out_size, void* d_ws, size_t ws_size,
                              hipStream_t stream) {
    const float* pos0 = (const float*)d_in[0];
    const float* pos1 = (const float*)d_in[1];
    const int* src = (const int*)d_in[2];
    const int* dstI = (const int*)d_in[3];
    const float* Wv = (const float*)d_in[4];
    const float* W1 = (const float*)d_in[5];
    const float* b1 = (const float*)d_in[6];
    const float* W2 = (const float*)d_in[7];
    const float* b2 = (const float*)d_in[8];
    const float* W3 = (const float*)d_in[9];
    const float* b3 = (const float*)d_in[10];
    unsigned char* ws = (unsigned char*)d_ws;
    float* out = (float*)d_out;

    prep_kernel<<<dim3(20), dim3(256), 0, stream>>>(W1, W2, W3, Wv, ws);
    edge_kernel<<<dim3(NBLK), dim3(256), 0, stream>>>(pos0, pos1, src, dstI, b1, b2, b3, ws, out);
}

// Round 3
// 442.124 us; speedup vs baseline: 1.7320x; 1.0691x over previous
//
#include <hip/hip_runtime.h>

#define NB 4
#define NN 10000
#define NE 320000
#define EPB 64
#define NBLK ((NB * NE) / EPB)   // 20000

typedef unsigned int uint;
typedef unsigned short ushort;
typedef __attribute__((ext_vector_type(8))) short short8;
typedef __attribute__((ext_vector_type(4))) float f32x4;

// d_ws layout (bytes). All tables are A-fragments for the transposed scheme:
//   A-frag: laneDim row = mt*16 + lm ; elem j -> k = kt*32 + (j>>2)*16 + la*4 + (j&3)
#define WS_W1T 0        // 8 mt * 64 = 512 frags * 16B = 8KB   (K=6 padded to 32)
#define WS_W2T 8192     // 8 mt * 4 kt * 64 = 2048 frags = 32KB
#define WS_W3T 40960    // 32KB
#define WS_WVT 73728    // 12 mt * 64 = 768 frags = 12KB  (rows = o*3+c, K=18 pad 32)

static __device__ __forceinline__ ushort f2bf(float f) {
    uint u = __float_as_uint(f);
    u += 0x7fffu + ((u >> 16) & 1u);
    return (ushort)(u >> 16);
}
static __device__ __forceinline__ uint pack2(float a, float b) {
    return (uint)f2bf(a) | ((uint)f2bf(b) << 16);
}
static __device__ __forceinline__ short8 u4s8(uint4 v) {
    union { uint4 u; short8 s; } x; x.u = v; return x.s;
}
static __device__ __forceinline__ float lk(float x) { return x >= 0.f ? x : 0.2f * x; }

// ---------------- prep: pack transposed weight fragment tables ----------------
__global__ void prep_kernel(const float* __restrict__ W1, const float* __restrict__ W2,
                            const float* __restrict__ W3, const float* __restrict__ Wv,
                            unsigned char* __restrict__ ws) {
    int tid = blockIdx.x * blockDim.x + threadIdx.x;
    if (tid < 4096) {
        const float* W = (tid < 2048) ? W2 : W3;
        uint4* dst = (uint4*)(ws + ((tid < 2048) ? WS_W2T : WS_W3T));
        int f = tid & 2047;                    // f = (mt*4 + kt)*64 + lane
        int lane = f & 63, kt = (f >> 6) & 3, mt = (f >> 8) & 7;
        int la = lane >> 4, lm = lane & 15;
        int n = mt * 16 + lm;
        uint w[4];
        #pragma unroll
        for (int jw = 0; jw < 4; ++jw) {
            int j0 = jw * 2, j1 = j0 + 1;
            int k0 = kt * 32 + (j0 >> 2) * 16 + la * 4 + (j0 & 3);
            int k1 = kt * 32 + (j1 >> 2) * 16 + la * 4 + (j1 & 3);
            w[jw] = pack2(W[n * 128 + k0], W[n * 128 + k1]);
        }
        dst[f] = make_uint4(w[0], w[1], w[2], w[3]);
    } else if (tid < 4608) {
        int f = tid - 4096;                    // f = mt*64 + lane, mt 0..7
        int lane = f & 63, mt = f >> 6;
        int la = lane >> 4, lm = lane & 15;
        int n = mt * 16 + lm;
        uint w[4];
        #pragma unroll
        for (int jw = 0; jw < 4; ++jw) {
            int j0 = jw * 2, j1 = j0 + 1;
            int k0 = (j0 >> 2) * 16 + la * 4 + (j0 & 3);
            int k1 = (j1 >> 2) * 16 + la * 4 + (j1 & 3);
            float f0 = (k0 < 6) ? W1[n * 6 + k0] : 0.f;
            float f1 = (k1 < 6) ? W1[n * 6 + k1] : 0.f;
            w[jw] = pack2(f0, f1);
        }
        ((uint4*)(ws + WS_W1T))[f] = make_uint4(w[0], w[1], w[2], w[3]);
    } else if (tid < 5376) {
        int f = tid - 4608;                    // f = mt*64 + lane, mt 0..11
        int lane = f & 63, mt = f >> 6;
        int la = lane >> 4, lm = lane & 15;
        int row = mt * 16 + lm;                // row = o*3 + c
        int o = row / 3, c = row - o * 3;
        uint w[4];
        #pragma unroll
        for (int jw = 0; jw < 4; ++jw) {
            float vv[2];
            #pragma unroll
            for (int dc = 0; dc < 2; ++dc) {
                int j = jw * 2 + dc;
                int k = (j >> 2) * 16 + la * 4 + (j & 3);
                int i = k / 3, cc = k - i * 3;
                vv[dc] = (k < 18 && cc == c) ? Wv[o * 6 + i] * (1.f / 3.f) : 0.f;
            }
            w[jw] = pack2(vv[0], vv[1]);
        }
        ((uint4*)(ws + WS_WVT))[f] = make_uint4(w[0], w[1], w[2], w[3]);
    }
}

// ---------------- main ----------------
__global__ __launch_bounds__(256, 3)
void edge_kernel(const float* __restrict__ pos0, const float* __restrict__ pos1,
                 const int* __restrict__ src, const int* __restrict__ dstI,
                 const float* __restrict__ b1, const float* __restrict__ b2,
                 const float* __restrict__ b3,
                 const unsigned char* __restrict__ ws, float* __restrict__ out) {
    __shared__ float s_pts[64][13];
    __shared__ float s_vecs[64][20];   // [e][i*3+c], 18 used
    __shared__ float s_norms[8][64];   // [i][e], 6 used
    __shared__ uint4 s_B[16 * 64];     // exchange: [wn][nt][kt][lane]

    const int tid = threadIdx.x;
    const int lane = tid & 63;
    const int wid = tid >> 6;
    const int wm = wid & 1;            // M-half (neurons)
    const int wn = wid >> 1;           // edge-half (32 edges = 2 nt)
    const int lm = lane & 15;
    const int la = lane >> 4;

    const int bid = blockIdx.x;
    const int b = bid / (NE / EPB);
    const int e0 = (bid % (NE / EPB)) * EPB;
    const size_t eg0 = (size_t)b * NE + e0;

    const uint4* W1T = (const uint4*)(ws + WS_W1T);
    const uint4* W2T = (const uint4*)(ws + WS_W2T);
    const uint4* W3T = (const uint4*)(ws + WS_W3T);
    const uint4* WVT = (const uint4*)(ws + WS_WVT);

    // --- phase A: gather endpoint positions ---
    {
        int le = tid & 63;
        int pt = tid >> 6;                       // 0:p0s 1:p0d 2:p1s 3:p1d
        int e = e0 + le;
        int node = (pt & 1) ? dstI[e] : src[e];
        const float* P = (pt < 2) ? pos0 : pos1;
        const float* p = P + ((size_t)b * NN + node) * 3;
        s_pts[le][pt * 3 + 0] = p[0];
        s_pts[le][pt * 3 + 1] = p[1];
        s_pts[le][pt * 3 + 2] = p[2];
    }
    __syncthreads();

    // --- phase B: vecs + norms (waves 0,1) ---
    {
        const int row = tid & 63;
        const int w = tid >> 6;
        if (w == 0) {
            float P[12];
            #pragma unroll
            for (int i = 0; i < 12; ++i) P[i] = s_pts[row][i];
            const int va[4] = {1, 3, 2, 3}, vb_[4] = {0, 2, 0, 1};
            float v[4][3];
            #pragma unroll
            for (int i = 0; i < 4; ++i) {
                #pragma unroll
                for (int c = 0; c < 3; ++c) v[i][c] = P[va[i] * 3 + c] - P[vb_[i] * 3 + c];
                s_norms[i][row] = sqrtf(v[i][0]*v[i][0] + v[i][1]*v[i][1] + v[i][2]*v[i][2]);
            }
            float4 t0 = {v[0][0], v[0][1], v[0][2], v[1][0]};
            float4 t1 = {v[1][1], v[1][2], v[2][0], v[2][1]};
            float4 t2 = {v[2][2], v[3][0], v[3][1], v[3][2]};
            *(float4*)&s_vecs[row][0] = t0;
            *(float4*)&s_vecs[row][4] = t1;
            *(float4*)&s_vecs[row][8] = t2;
        } else if (w == 1) {
            float P[12];
            #pragma unroll
            for (int i = 0; i < 12; ++i) P[i] = s_pts[row][i];
            float v4[3], v5[3];
            #pragma unroll
            for (int c = 0; c < 3; ++c) {
                v4[c] = P[6 + c] - P[3 + c];   // p1s - p0d
                v5[c] = P[9 + c] - P[0 + c];   // p1d - p0s
            }
            s_norms[4][row] = sqrtf(v4[0]*v4[0] + v4[1]*v4[1] + v4[2]*v4[2]);
            s_norms[5][row] = sqrtf(v5[0]*v5[0] + v5[1]*v5[1] + v5[2]*v5[2]);
            float4 t = {v4[0], v4[1], v4[2], v5[0]};
            *(float4*)&s_vecs[row][12] = t;
            float2 t2 = {v5[1], v5[2]};
            *(float2*)&s_vecs[row][16] = t2;
        }
    }
    __syncthreads();

    const f32x4 zero4 = {0.f, 0.f, 0.f, 0.f};
    f32x4 acc[4][2];

    // --- layer 1: B-frags from norms, A = W1T ---
    {
        uint4 vb1[2];
        #pragma unroll
        for (int nt = 0; nt < 2; ++nt) {
            int e = (wn * 2 + nt) * 16 + lm;
            uint c0 = 0, c1 = 0;
            if (la == 0) {
                c0 = pack2(s_norms[0][e], s_norms[1][e]);
                c1 = pack2(s_norms[2][e], s_norms[3][e]);
            } else if (la == 1) {
                c0 = pack2(s_norms[4][e], s_norms[5][e]);
            }
            vb1[nt] = make_uint4(c0, c1, 0u, 0u);
        }
        uint4 w1f[4];
        #pragma unroll
        for (int mtl = 0; mtl < 4; ++mtl) w1f[mtl] = W1T[(wm * 4 + mtl) * 64 + lane];
        #pragma unroll
        for (int mtl = 0; mtl < 4; ++mtl)
            #pragma unroll
            for (int nt = 0; nt < 2; ++nt)
                acc[mtl][nt] = __builtin_amdgcn_mfma_f32_16x16x32_bf16(
                    u4s8(w1f[mtl]), u4s8(vb1[nt]), zero4, 0, 0, 0);
    }
    // bias1 + leaky, pack, write exchange
    #pragma unroll
    for (int mtl = 0; mtl < 4; ++mtl) {
        float4 bc = *(const float4*)&b1[(wm * 4 + mtl) * 16 + la * 4];
        #pragma unroll
        for (int nt = 0; nt < 2; ++nt) {
            acc[mtl][nt][0] = lk(acc[mtl][nt][0] + bc.x);
            acc[mtl][nt][1] = lk(acc[mtl][nt][1] + bc.y);
            acc[mtl][nt][2] = lk(acc[mtl][nt][2] + bc.z);
            acc[mtl][nt][3] = lk(acc[mtl][nt][3] + bc.w);
        }
    }
    #pragma unroll
    for (int nt = 0; nt < 2; ++nt)
        #pragma unroll
        for (int t = 0; t < 2; ++t) {
            f32x4 ha = acc[2 * t][nt], hb = acc[2 * t + 1][nt];
            s_B[((wn * 2 + nt) * 4 + wm * 2 + t) * 64 + lane] =
                make_uint4(pack2(ha[0], ha[1]), pack2(ha[2], ha[3]),
                           pack2(hb[0], hb[1]), pack2(hb[2], hb[3]));
        }
    __syncthreads();

    uint4 vb[2][4];
    #pragma unroll
    for (int nt = 0; nt < 2; ++nt)
        #pragma unroll
        for (int kt = 0; kt < 4; ++kt)
            vb[nt][kt] = s_B[((wn * 2 + nt) * 4 + kt) * 64 + lane];
    __syncthreads();   // guard: reads done before exch-2 writes

    // --- layer 2 ---
    {
        uint4 wf[4][4];
        #pragma unroll
        for (int mtl = 0; mtl < 4; ++mtl)
            #pragma unroll
            for (int kt = 0; kt < 4; ++kt)
                wf[mtl][kt] = W2T[((wm * 4 + mtl) * 4 + kt) * 64 + lane];
        #pragma unroll
        for (int mtl = 0; mtl < 4; ++mtl)
            #pragma unroll
            for (int nt = 0; nt < 2; ++nt) acc[mtl][nt] = zero4;
        #pragma unroll
        for (int kt = 0; kt < 4; ++kt)
            #pragma unroll
            for (int mtl = 0; mtl < 4; ++mtl)
                #pragma unroll
                for (int nt = 0; nt < 2; ++nt)
                    acc[mtl][nt] = __builtin_amdgcn_mfma_f32_16x16x32_bf16(
                        u4s8(wf[mtl][kt]), u4s8(vb[nt][kt]), acc[mtl][nt], 0, 0, 0);
    }
    #pragma unroll
    for (int mtl = 0; mtl < 4; ++mtl) {
        float4 bc = *(const float4*)&b2[(wm * 4 + mtl) * 16 + la * 4];
        #pragma unroll
        for (int nt = 0; nt < 2; ++nt) {
            acc[mtl][nt][0] = lk(acc[mtl][nt][0] + bc.x);
            acc[mtl][nt][1] = lk(acc[mtl][nt][1] + bc.y);
            acc[mtl][nt][2] = lk(acc[mtl][nt][2] + bc.z);
            acc[mtl][nt][3] = lk(acc[mtl][nt][3] + bc.w);
        }
    }
    #pragma unroll
    for (int nt = 0; nt < 2; ++nt)
        #pragma unroll
        for (int t = 0; t < 2; ++t) {
            f32x4 ha = acc[2 * t][nt], hb = acc[2 * t + 1][nt];
            s_B[((wn * 2 + nt) * 4 + wm * 2 + t) * 64 + lane] =
                make_uint4(pack2(ha[0], ha[1]), pack2(ha[2], ha[3]),
                           pack2(hb[0], hb[1]), pack2(hb[2], hb[3]));
        }
    __syncthreads();

    #pragma unroll
    for (int nt = 0; nt < 2; ++nt)
        #pragma unroll
        for (int kt = 0; kt < 4; ++kt)
            vb[nt][kt] = s_B[((wn * 2 + nt) * 4 + kt) * 64 + lane];

    // --- layer 3 ---
    {
        uint4 wf[4][4];
        #pragma unroll
        for (int mtl = 0; mtl < 4; ++mtl)
            #pragma unroll
            for (int kt = 0; kt < 4; ++kt)
                wf[mtl][kt] = W3T[((wm * 4 + mtl) * 4 + kt) * 64 + lane];
        #pragma unroll
        for (int mtl = 0; mtl < 4; ++mtl)
            #pragma unroll
            for (int nt = 0; nt < 2; ++nt) acc[mtl][nt] = zero4;
        #pragma unroll
        for (int kt = 0; kt < 4; ++kt)
            #pragma unroll
            for (int mtl = 0; mtl < 4; ++mtl)
                #pragma unroll
                for (int nt = 0; nt < 2; ++nt)
                    acc[mtl][nt] = __builtin_amdgcn_mfma_f32_16x16x32_bf16(
                        u4s8(wf[mtl][kt]), u4s8(vb[nt][kt]), acc[mtl][nt], 0, 0, 0);
    }
    // bias3 + direct a_out stores: lane stores float4 (contig n) per (mtl, nt)
    #pragma unroll
    for (int mtl = 0; mtl < 4; ++mtl) {
        float4 bc = *(const float4*)&b3[(wm * 4 + mtl) * 16 + la * 4];
        #pragma unroll
        for (int nt = 0; nt < 2; ++nt) {
            float4 v = {acc[mtl][nt][0] + bc.x, acc[mtl][nt][1] + bc.y,
                        acc[mtl][nt][2] + bc.z, acc[mtl][nt][3] + bc.w};
            size_t e = eg0 + (wn * 2 + nt) * 16 + lm;
            *(float4*)&out[e * 128 + (wm * 4 + mtl) * 16 + la * 4] = v;
        }
    }

    // --- v_out: MFMA with expanded Wv (rows = o*3+c), direct stores ---
    {
        uint4 vbv[2];
        #pragma unroll
        for (int nt = 0; nt < 2; ++nt) {
            int e = (wn * 2 + nt) * 16 + lm;
            int base = la * 4;
            uint c0 = pack2(s_vecs[e][base], s_vecs[e][base + 1]);
            uint c1 = pack2(s_vecs[e][base + 2], s_vecs[e][base + 3]);
            uint c2 = (la == 0) ? pack2(s_vecs[e][16], s_vecs[e][17]) : 0u;
            vbv[nt] = make_uint4(c0, c1, c2, 0u);
        }
        float* vout = out + (size_t)NB * NE * 128;
        #pragma unroll
        for (int m6 = 0; m6 < 6; ++m6) {
            uint4 wv = WVT[(wm * 6 + m6) * 64 + lane];
            #pragma unroll
            for (int nt = 0; nt < 2; ++nt) {
                f32x4 av = __builtin_amdgcn_mfma_f32_16x16x32_bf16(
                    u4s8(wv), u4s8(vbv[nt]), zero4, 0, 0, 0);
                size_t e = eg0 + (wn * 2 + nt) * 16 + lm;
                float4 v = {av[0], av[1], av[2], av[3]};
                *(float4*)&vout[e * 192 + (wm * 6 + m6) * 16 + la * 4] = v;
            }
        }
    }
}

extern "C" void kernel_launch(void* const* d_in, const int* in_sizes, int n_in,
                              void* d_out, int out_size, void* d_ws, size_t ws_size,
                              hipStream_t stream) {
    const float* pos0 = (const float*)d_in[0];
    const float* pos1 = (const float*)d_in[1];
    const int* src = (const int*)d_in[2];
    const int* dstI = (const int*)d_in[3];
    const float* Wv = (const float*)d_in[4];
    const float* W1 = (const float*)d_in[5];
    const float* b1 = (const float*)d_in[6];
    const float* W2 = (const float*)d_in[7];
    const float* b2 = (const float*)d_in[8];
    const float* W3 = (const float*)d_in[9];
    const float* b3 = (const float*)d_in[10];
    unsigned char* ws = (unsigned char*)d_ws;
    float* out = (float*)d_out;

    prep_kernel<<<dim3(21), dim3(256), 0, stream>>>(W1, W2, W3, Wv, ws);
    edge_kernel<<<dim3(NBLK), dim3(256), 0, stream>>>(pos0, pos1, src, dstI, b1, b2, b3, ws, out);
}

// Round 4
// 435.823 us; speedup vs baseline: 1.7571x; 1.0145x over previous
//
#include <hip/hip_runtime.h>

#define NB 4
#define NN 10000
#define NE 320000
#define EPB 128
#define NBLK ((NB * NE) / EPB)   // 10000

typedef unsigned int uint;
typedef unsigned short ushort;
typedef __attribute__((ext_vector_type(8))) short short8;
typedef __attribute__((ext_vector_type(4))) float f32x4;

// d_ws layout (bytes). All tables are A-fragments for the transposed scheme:
//   A-frag: laneDim row = mt*16 + lm ; elem j -> k = kt*32 + (j>>2)*16 + la*4 + (j&3)
#define WS_W1T 0        // 8 mt * 64 = 512 frags * 16B = 8KB   (K=6 padded to 32)
#define WS_W2T 8192     // 8 mt * 4 kt * 64 = 2048 frags = 32KB
#define WS_W3T 40960    // 32KB
#define WS_WVT 73728    // 12 mt * 64 = 768 frags = 12KB  (rows = o*3+c, K=18 pad 32)

static __device__ __forceinline__ ushort f2bf(float f) {
    uint u = __float_as_uint(f);
    u += 0x7fffu + ((u >> 16) & 1u);
    return (ushort)(u >> 16);
}
static __device__ __forceinline__ uint pack2(float a, float b) {
    return (uint)f2bf(a) | ((uint)f2bf(b) << 16);
}
// single-instr RNE pack of two f32 -> 2x bf16 (compiler can't derive from bit math)
static __device__ __forceinline__ uint cvtpk(float a, float b) {
    uint r;
    asm("v_cvt_pk_bf16_f32 %0, %1, %2" : "=v"(r) : "v"(a), "v"(b));
    return r;
}
static __device__ __forceinline__ short8 u4s8(uint4 v) {
    union { uint4 u; short8 s; } x; x.u = v; return x.s;
}
static __device__ __forceinline__ f32x4 MF(uint4 a, uint4 b, f32x4 c) {
    return __builtin_amdgcn_mfma_f32_16x16x32_bf16(u4s8(a), u4s8(b), c, 0, 0, 0);
}

// ---------------- prep: pack transposed weight fragment tables ----------------
__global__ void prep_kernel(const float* __restrict__ W1, const float* __restrict__ W2,
                            const float* __restrict__ W3, const float* __restrict__ Wv,
                            unsigned char* __restrict__ ws) {
    int tid = blockIdx.x * blockDim.x + threadIdx.x;
    if (tid < 4096) {
        const float* W = (tid < 2048) ? W2 : W3;
        uint4* dst = (uint4*)(ws + ((tid < 2048) ? WS_W2T : WS_W3T));
        int f = tid & 2047;                    // f = (mt*4 + kt)*64 + lane
        int lane = f & 63, kt = (f >> 6) & 3, mt = (f >> 8) & 7;
        int la = lane >> 4, lm = lane & 15;
        int n = mt * 16 + lm;
        uint w[4];
        #pragma unroll
        for (int jw = 0; jw < 4; ++jw) {
            int j0 = jw * 2, j1 = j0 + 1;
            int k0 = kt * 32 + (j0 >> 2) * 16 + la * 4 + (j0 & 3);
            int k1 = kt * 32 + (j1 >> 2) * 16 + la * 4 + (j1 & 3);
            w[jw] = pack2(W[n * 128 + k0], W[n * 128 + k1]);
        }
        dst[f] = make_uint4(w[0], w[1], w[2], w[3]);
    } else if (tid < 4608) {
        int f = tid - 4096;                    // f = mt*64 + lane, mt 0..7
        int lane = f & 63, mt = f >> 6;
        int la = lane >> 4, lm = lane & 15;
        int n = mt * 16 + lm;
        uint w[4];
        #pragma unroll
        for (int jw = 0; jw < 4; ++jw) {
            int j0 = jw * 2, j1 = j0 + 1;
            int k0 = (j0 >> 2) * 16 + la * 4 + (j0 & 3);
            int k1 = (j1 >> 2) * 16 + la * 4 + (j1 & 3);
            float f0 = (k0 < 6) ? W1[n * 6 + k0] : 0.f;
            float f1 = (k1 < 6) ? W1[n * 6 + k1] : 0.f;
            w[jw] = pack2(f0, f1);
        }
        ((uint4*)(ws + WS_W1T))[f] = make_uint4(w[0], w[1], w[2], w[3]);
    } else if (tid < 5376) {
        int f = tid - 4608;                    // f = mt*64 + lane, mt 0..11
        int lane = f & 63, mt = f >> 6;
        int la = lane >> 4, lm = lane & 15;
        int row = mt * 16 + lm;                // row = o*3 + c
        int o = row / 3, c = row - o * 3;
        uint w[4];
        #pragma unroll
        for (int jw = 0; jw < 4; ++jw) {
            float vv[2];
            #pragma unroll
            for (int dc = 0; dc < 2; ++dc) {
                int j = jw * 2 + dc;
                int k = (j >> 2) * 16 + la * 4 + (j & 3);
                int i = k / 3, cc = k - i * 3;
                vv[dc] = (k < 18 && cc == c) ? Wv[o * 6 + i] * (1.f / 3.f) : 0.f;
            }
            w[jw] = pack2(vv[0], vv[1]);
        }
        ((uint4*)(ws + WS_WVT))[f] = make_uint4(w[0], w[1], w[2], w[3]);
    }
}

// ---------------- main: fully wave-autonomous, ZERO barriers ----------------
// Each wave owns 32 edges end-to-end. LDS sliced per wave (wave-ordered DS ops,
// no __syncthreads). In-register layer handoff: C/D (n=mt*16+la*4+r, e=lm) IS
// the next layer's B-frag (k=kt*32+(j>>2)*16+la*4+(j&3)) at mt=2kt+(j>>2), r=j&3.
__global__ __launch_bounds__(256, 3)
void edge_kernel(const float* __restrict__ pos0, const float* __restrict__ pos1,
                 const int* __restrict__ src, const int* __restrict__ dstI,
                 const float* __restrict__ b1, const float* __restrict__ b2,
                 const float* __restrict__ b3,
                 const unsigned char* __restrict__ ws, float* __restrict__ out) {
    __shared__ float s_pts[128][13];
    __shared__ float s_vecs[128][20];   // 18 used
    __shared__ float s_norms[6][128];

    const int tid = threadIdx.x;
    const int lane = tid & 63;
    const int w = tid >> 6;
    const int lm = lane & 15;
    const int la = lane >> 4;
    const int ew0 = w * 32;            // wave's local edge base

    const int bid = blockIdx.x;
    const int b = bid / (NE / EPB);
    const int e0 = (bid % (NE / EPB)) * EPB;
    const size_t eg0 = (size_t)b * NE + e0;

    const uint4* W1T = (const uint4*)(ws + WS_W1T);
    const uint4* W2T = (const uint4*)(ws + WS_W2T);
    const uint4* W3T = (const uint4*)(ws + WS_W3T);
    const uint4* WVT = (const uint4*)(ws + WS_WVT);

    // --- gather: lane handles edge (lane&31), side (lane>>5); both pos0 & pos1 ---
    {
        const int el = ew0 + (lane & 31);
        const int side = lane >> 5;
        const int e = e0 + el;
        const int node = side ? dstI[e] : src[e];
        const size_t pb = ((size_t)b * NN + node) * 3;
        float a0 = pos0[pb], a1 = pos0[pb + 1], a2 = pos0[pb + 2];
        float c0 = pos1[pb], c1 = pos1[pb + 1], c2 = pos1[pb + 2];
        s_pts[el][side * 3 + 0] = a0;
        s_pts[el][side * 3 + 1] = a1;
        s_pts[el][side * 3 + 2] = a2;
        s_pts[el][6 + side * 3 + 0] = c0;
        s_pts[el][6 + side * 3 + 1] = c1;
        s_pts[el][6 + side * 3 + 2] = c2;
    }

    // --- vecs + norms (wave-internal; DS ops are wave-ordered) ---
    {
        const int el = ew0 + (lane & 31);
        const int grp = lane >> 5;
        float P[12];
        #pragma unroll
        for (int i = 0; i < 12; ++i) P[i] = s_pts[el][i];
        if (grp == 0) {
            const int va[4] = {1, 3, 2, 3}, vbx[4] = {0, 2, 0, 1};
            float v[4][3];
            #pragma unroll
            for (int i = 0; i < 4; ++i) {
                #pragma unroll
                for (int c = 0; c < 3; ++c) v[i][c] = P[va[i] * 3 + c] - P[vbx[i] * 3 + c];
                s_norms[i][el] = sqrtf(v[i][0]*v[i][0] + v[i][1]*v[i][1] + v[i][2]*v[i][2]);
            }
            float4 t0 = {v[0][0], v[0][1], v[0][2], v[1][0]};
            float4 t1 = {v[1][1], v[1][2], v[2][0], v[2][1]};
            float4 t2 = {v[2][2], v[3][0], v[3][1], v[3][2]};
            *(float4*)&s_vecs[el][0] = t0;
            *(float4*)&s_vecs[el][4] = t1;
            *(float4*)&s_vecs[el][8] = t2;
        } else {
            float v4[3], v5[3];
            #pragma unroll
            for (int c = 0; c < 3; ++c) {
                v4[c] = P[6 + c] - P[3 + c];   // p1s - p0d
                v5[c] = P[9 + c] - P[0 + c];   // p1d - p0s
            }
            s_norms[4][el] = sqrtf(v4[0]*v4[0] + v4[1]*v4[1] + v4[2]*v4[2]);
            s_norms[5][el] = sqrtf(v5[0]*v5[0] + v5[1]*v5[1] + v5[2]*v5[2]);
            float4 t = {v4[0], v4[1], v4[2], v5[0]};
            *(float4*)&s_vecs[el][12] = t;
            float2 t2 = {v5[1], v5[2]};
            *(float2*)&s_vecs[el][16] = t2;
        }
    }

    const f32x4 zero4 = {0.f, 0.f, 0.f, 0.f};

    // --- v_out FIRST (60% of output bytes starts draining under MLP compute) ---
    {
        uint4 vbv[2];
        #pragma unroll
        for (int nt = 0; nt < 2; ++nt) {
            const int e = ew0 + nt * 16 + lm;
            float4 q = *(const float4*)&s_vecs[e][la * 4];
            uint c2 = 0;
            if (la == 0) c2 = cvtpk(s_vecs[e][16], s_vecs[e][17]);
            vbv[nt] = make_uint4(cvtpk(q.x, q.y), cvtpk(q.z, q.w), c2, 0u);
        }
        uint4 wv[12];
        #pragma unroll
        for (int mt = 0; mt < 12; ++mt) wv[mt] = WVT[mt * 64 + lane];
        float* vout = out + (size_t)NB * NE * 128;
        #pragma unroll
        for (int mt = 0; mt < 12; ++mt)
            #pragma unroll
            for (int nt = 0; nt < 2; ++nt) {
                f32x4 av = MF(wv[mt], vbv[nt], zero4);
                const size_t e = eg0 + ew0 + nt * 16 + lm;
                *(f32x4*)&vout[e * 192 + mt * 16 + la * 4] = av;
            }
    }

    // --- layer 1 ---
    f32x4 acc[8][2];
    {
        uint4 vb1[2];
        #pragma unroll
        for (int nt = 0; nt < 2; ++nt) {
            const int e = ew0 + nt * 16 + lm;
            uint c0 = 0, c1 = 0;
            if (la == 0) {
                c0 = cvtpk(s_norms[0][e], s_norms[1][e]);
                c1 = cvtpk(s_norms[2][e], s_norms[3][e]);
            } else if (la == 1) {
                c0 = cvtpk(s_norms[4][e], s_norms[5][e]);
            }
            vb1[nt] = make_uint4(c0, c1, 0u, 0u);
        }
        uint4 w1f[8];
        #pragma unroll
        for (int mt = 0; mt < 8; ++mt) w1f[mt] = W1T[mt * 64 + lane];
        #pragma unroll
        for (int mt = 0; mt < 8; ++mt)
            #pragma unroll
            for (int nt = 0; nt < 2; ++nt)
                acc[mt][nt] = MF(w1f[mt], vb1[nt], zero4);
    }
    uint4 vb[2][4];
    // epilogue 1: bias + leaky(max(x,0.2x)) + in-register pack to next B-frags
    #pragma unroll
    for (int mt = 0; mt < 8; ++mt) {
        f32x4 bc = *(const f32x4*)&b1[mt * 16 + la * 4];
        #pragma unroll
        for (int nt = 0; nt < 2; ++nt)
            #pragma unroll
            for (int r = 0; r < 4; ++r) {
                float x = acc[mt][nt][r] + bc[r];
                acc[mt][nt][r] = fmaxf(x, 0.2f * x);
            }
    }
    #pragma unroll
    for (int nt = 0; nt < 2; ++nt)
        #pragma unroll
        for (int kt = 0; kt < 4; ++kt)
            vb[nt][kt] = make_uint4(
                cvtpk(acc[2*kt][nt][0], acc[2*kt][nt][1]),
                cvtpk(acc[2*kt][nt][2], acc[2*kt][nt][3]),
                cvtpk(acc[2*kt+1][nt][0], acc[2*kt+1][nt][1]),
                cvtpk(acc[2*kt+1][nt][2], acc[2*kt+1][nt][3]));

    // --- layer 2 ---
    #pragma unroll
    for (int mt = 0; mt < 8; ++mt)
        #pragma unroll
        for (int nt = 0; nt < 2; ++nt) acc[mt][nt] = zero4;
    #pragma unroll
    for (int kt = 0; kt < 4; ++kt) {
        uint4 wf[8];
        #pragma unroll
        for (int mt = 0; mt < 8; ++mt) wf[mt] = W2T[(mt * 4 + kt) * 64 + lane];
        #pragma unroll
        for (int mt = 0; mt < 8; ++mt)
            #pragma unroll
            for (int nt = 0; nt < 2; ++nt)
                acc[mt][nt] = MF(wf[mt], vb[nt][kt], acc[mt][nt]);
    }
    // epilogue 2
    #pragma unroll
    for (int mt = 0; mt < 8; ++mt) {
        f32x4 bc = *(const f32x4*)&b2[mt * 16 + la * 4];
        #pragma unroll
        for (int nt = 0; nt < 2; ++nt)
            #pragma unroll
            for (int r = 0; r < 4; ++r) {
                float x = acc[mt][nt][r] + bc[r];
                acc[mt][nt][r] = fmaxf(x, 0.2f * x);
            }
    }
    #pragma unroll
    for (int nt = 0; nt < 2; ++nt)
        #pragma unroll
        for (int kt = 0; kt < 4; ++kt)
            vb[nt][kt] = make_uint4(
                cvtpk(acc[2*kt][nt][0], acc[2*kt][nt][1]),
                cvtpk(acc[2*kt][nt][2], acc[2*kt][nt][3]),
                cvtpk(acc[2*kt+1][nt][0], acc[2*kt+1][nt][1]),
                cvtpk(acc[2*kt+1][nt][2], acc[2*kt+1][nt][3]));

    // --- layer 3 ---
    #pragma unroll
    for (int mt = 0; mt < 8; ++mt)
        #pragma unroll
        for (int nt = 0; nt < 2; ++nt) acc[mt][nt] = zero4;
    #pragma unroll
    for (int kt = 0; kt < 4; ++kt) {
        uint4 wf[8];
        #pragma unroll
        for (int mt = 0; mt < 8; ++mt) wf[mt] = W3T[(mt * 4 + kt) * 64 + lane];
        #pragma unroll
        for (int mt = 0; mt < 8; ++mt)
            #pragma unroll
            for (int nt = 0; nt < 2; ++nt)
                acc[mt][nt] = MF(wf[mt], vb[nt][kt], acc[mt][nt]);
    }
    // bias 3 + direct a_out stores (16B/lane, 64B contiguous per edge per mt)
    #pragma unroll
    for (int mt = 0; mt < 8; ++mt) {
        f32x4 bc = *(const f32x4*)&b3[mt * 16 + la * 4];
        #pragma unroll
        for (int nt = 0; nt < 2; ++nt) {
            f32x4 v = acc[mt][nt] + bc;
            const size_t e = eg0 + ew0 + nt * 16 + lm;
            *(f32x4*)&out[e * 128 + mt * 16 + la * 4] = v;
        }
    }
}

extern "C" void kernel_launch(void* const* d_in, const int* in_sizes, int n_in,
                              void* d_out, int out_size, void* d_ws, size_t ws_size,
                              hipStream_t stream) {
    const float* pos0 = (const float*)d_in[0];
    const float* pos1 = (const float*)d_in[1];
    const int* src = (const int*)d_in[2];
    const int* dstI = (const int*)d_in[3];
    const float* Wv = (const float*)d_in[4];
    const float* W1 = (const float*)d_in[5];
    const float* b1 = (const float*)d_in[6];
    const float* W2 = (const float*)d_in[7];
    const float* b2 = (const float*)d_in[8];
    const float* W3 = (const float*)d_in[9];
    const float* b3 = (const float*)d_in[10];
    unsigned char* ws = (unsigned char*)d_ws;
    float* out = (float*)d_out;

    prep_kernel<<<dim3(21), dim3(256), 0, stream>>>(W1, W2, W3, Wv, ws);
    edge_kernel<<<dim3(NBLK), dim3(256), 0, stream>>>(pos0, pos1, src, dstI, b1, b2, b3, ws, out);
}

// Round 5
// 390.897 us; speedup vs baseline: 1.9590x; 1.1149x over previous
//
#include <hip/hip_runtime.h>

#define NB 4
#define NN 10000
#define NE 320000
#define EPB 128
#define NPAIR (NE / EPB)          // 2500 tiles per batch
#define NBLK (2 * NB * NPAIR)     // 20000 blocks: even=v_out, odd=a_out

typedef unsigned int uint;
typedef unsigned short ushort;
typedef __attribute__((ext_vector_type(8))) short short8;
typedef __attribute__((ext_vector_type(4))) float f32x4;

// d_ws layout (bytes). All tables are A-fragments for the transposed scheme:
//   A-frag: laneDim row = mt*16 + lm ; elem j -> k = kt*32 + (j>>2)*16 + la*4 + (j&3)
#define WS_W1T 0        // 8 mt * 64 = 512 frags * 16B = 8KB   (K=6 padded to 32)
#define WS_W2T 8192     // 8 mt * 4 kt * 64 = 2048 frags = 32KB
#define WS_W3T 40960    // 32KB
#define WS_WVT 73728    // 12 mt * 64 = 768 frags = 12KB  (rows = o*3+c, K=18 pad 32)

static __device__ __forceinline__ ushort f2bf(float f) {
    uint u = __float_as_uint(f);
    u += 0x7fffu + ((u >> 16) & 1u);
    return (ushort)(u >> 16);
}
static __device__ __forceinline__ uint pack2(float a, float b) {
    return (uint)f2bf(a) | ((uint)f2bf(b) << 16);
}
static __device__ __forceinline__ uint cvtpk(float a, float b) {
    uint r;
    asm("v_cvt_pk_bf16_f32 %0, %1, %2" : "=v"(r) : "v"(a), "v"(b));
    return r;
}
static __device__ __forceinline__ short8 u4s8(uint4 v) {
    union { uint4 u; short8 s; } x; x.u = v; return x.s;
}
static __device__ __forceinline__ f32x4 MF(uint4 a, uint4 b, f32x4 c) {
    return __builtin_amdgcn_mfma_f32_16x16x32_bf16(u4s8(a), u4s8(b), c, 0, 0, 0);
}

// ---------------- prep: pack transposed weight fragment tables ----------------
__global__ void prep_kernel(const float* __restrict__ W1, const float* __restrict__ W2,
                            const float* __restrict__ W3, const float* __restrict__ Wv,
                            unsigned char* __restrict__ ws) {
    int tid = blockIdx.x * blockDim.x + threadIdx.x;
    if (tid < 4096) {
        const float* W = (tid < 2048) ? W2 : W3;
        uint4* dst = (uint4*)(ws + ((tid < 2048) ? WS_W2T : WS_W3T));
        int f = tid & 2047;                    // f = (mt*4 + kt)*64 + lane
        int lane = f & 63, kt = (f >> 6) & 3, mt = (f >> 8) & 7;
        int la = lane >> 4, lm = lane & 15;
        int n = mt * 16 + lm;
        uint w[4];
        #pragma unroll
        for (int jw = 0; jw < 4; ++jw) {
            int j0 = jw * 2, j1 = j0 + 1;
            int k0 = kt * 32 + (j0 >> 2) * 16 + la * 4 + (j0 & 3);
            int k1 = kt * 32 + (j1 >> 2) * 16 + la * 4 + (j1 & 3);
            w[jw] = pack2(W[n * 128 + k0], W[n * 128 + k1]);
        }
        dst[f] = make_uint4(w[0], w[1], w[2], w[3]);
    } else if (tid < 4608) {
        int f = tid - 4096;                    // f = mt*64 + lane, mt 0..7
        int lane = f & 63, mt = f >> 6;
        int la = lane >> 4, lm = lane & 15;
        int n = mt * 16 + lm;
        uint w[4];
        #pragma unroll
        for (int jw = 0; jw < 4; ++jw) {
            int j0 = jw * 2, j1 = j0 + 1;
            int k0 = (j0 >> 2) * 16 + la * 4 + (j0 & 3);
            int k1 = (j1 >> 2) * 16 + la * 4 + (j1 & 3);
            float f0 = (k0 < 6) ? W1[n * 6 + k0] : 0.f;
            float f1 = (k1 < 6) ? W1[n * 6 + k1] : 0.f;
            w[jw] = pack2(f0, f1);
        }
        ((uint4*)(ws + WS_W1T))[f] = make_uint4(w[0], w[1], w[2], w[3]);
    } else if (tid < 5376) {
        int f = tid - 4608;                    // f = mt*64 + lane, mt 0..11
        int lane = f & 63, mt = f >> 6;
        int la = lane >> 4, lm = lane & 15;
        int row = mt * 16 + lm;                // row = o*3 + c
        int o = row / 3, c = row - o * 3;
        uint w[4];
        #pragma unroll
        for (int jw = 0; jw < 4; ++jw) {
            float vv[2];
            #pragma unroll
            for (int dc = 0; dc < 2; ++dc) {
                int j = jw * 2 + dc;
                int k = (j >> 2) * 16 + la * 4 + (j & 3);
                int i = k / 3, cc = k - i * 3;
                vv[dc] = (k < 18 && cc == c) ? Wv[o * 6 + i] * (1.f / 3.f) : 0.f;
            }
            w[jw] = pack2(vv[0], vv[1]);
        }
        ((uint4*)(ws + WS_WVT))[f] = make_uint4(w[0], w[1], w[2], w[3]);
    }
}

// ---------------- main: interleaved vout/aout blocks ----------------
// even bid: v_out streamer (zero barriers). odd bid: MLP -> a_out (one barrier).
// LDS overlay: [0,6656) s_pts both | [6656,...) vout: s_vecs (10.2KB)
//                                   | aout: s_norms (3KB) + s_W2 (32KB)
__global__ __launch_bounds__(256, 3)
void edge_kernel(const float* __restrict__ pos0, const float* __restrict__ pos1,
                 const int* __restrict__ src, const int* __restrict__ dstI,
                 const float* __restrict__ b1, const float* __restrict__ b2,
                 const float* __restrict__ b3,
                 const unsigned char* __restrict__ ws, float* __restrict__ out) {
    __shared__ __align__(16) char smem[42496];
    float (*s_pts)[13] = (float(*)[13])smem;

    const int tid = threadIdx.x;
    const int lane = tid & 63;
    const int w = tid >> 6;
    const int lm = lane & 15;
    const int la = lane >> 4;
    const int ew0 = w * 32;            // wave's local edge base
    const int el = ew0 + (lane & 31);
    const int side = lane >> 5;

    const int bid = blockIdx.x;
    const int kind = bid & 1;
    const int idx = bid >> 1;
    const int b = idx / NPAIR;
    const int e0 = (idx % NPAIR) * EPB;
    const size_t eg0 = (size_t)b * NE + e0;

    const f32x4 zero4 = {0.f, 0.f, 0.f, 0.f};

    // --- gather endpoints: lane covers (edge=lane&31, side); wave-local ---
    {
        const int e = e0 + el;
        const int node = side ? dstI[e] : src[e];
        const size_t pb = ((size_t)b * NN + node) * 3;
        float a0 = pos0[pb], a1 = pos0[pb + 1], a2 = pos0[pb + 2];
        float c0 = pos1[pb], c1 = pos1[pb + 1], c2 = pos1[pb + 2];
        s_pts[el][side * 3 + 0] = a0;
        s_pts[el][side * 3 + 1] = a1;
        s_pts[el][side * 3 + 2] = a2;
        s_pts[el][6 + side * 3 + 0] = c0;
        s_pts[el][6 + side * 3 + 1] = c1;
        s_pts[el][6 + side * 3 + 2] = c2;
    }

    if (kind == 0) {
        // ================= v_out streamer =================
        float (*s_vecs)[20] = (float(*)[20])(smem + 6656);
        {
            float P[12];
            #pragma unroll
            for (int i = 0; i < 12; ++i) P[i] = s_pts[el][i];
            if (side == 0) {
                const int va[4] = {1, 3, 2, 3}, vbx[4] = {0, 2, 0, 1};
                float v[4][3];
                #pragma unroll
                for (int i = 0; i < 4; ++i)
                    #pragma unroll
                    for (int c = 0; c < 3; ++c) v[i][c] = P[va[i] * 3 + c] - P[vbx[i] * 3 + c];
                float4 t0 = {v[0][0], v[0][1], v[0][2], v[1][0]};
                float4 t1 = {v[1][1], v[1][2], v[2][0], v[2][1]};
                float4 t2 = {v[2][2], v[3][0], v[3][1], v[3][2]};
                *(float4*)&s_vecs[el][0] = t0;
                *(float4*)&s_vecs[el][4] = t1;
                *(float4*)&s_vecs[el][8] = t2;
            } else {
                float v4[3], v5[3];
                #pragma unroll
                for (int c = 0; c < 3; ++c) {
                    v4[c] = P[6 + c] - P[3 + c];   // p1s - p0d
                    v5[c] = P[9 + c] - P[0 + c];   // p1d - p0s
                }
                float4 t = {v4[0], v4[1], v4[2], v5[0]};
                *(float4*)&s_vecs[el][12] = t;
                float2 t2 = {v5[1], v5[2]};
                *(float2*)&s_vecs[el][16] = t2;
            }
        }
        uint4 vbv[2];
        #pragma unroll
        for (int nt = 0; nt < 2; ++nt) {
            const int e = ew0 + nt * 16 + lm;
            float4 q = *(const float4*)&s_vecs[e][la * 4];
            uint c2 = 0;
            if (la == 0) c2 = cvtpk(s_vecs[e][16], s_vecs[e][17]);
            vbv[nt] = make_uint4(cvtpk(q.x, q.y), cvtpk(q.z, q.w), c2, 0u);
        }
        const uint4* WVT = (const uint4*)(ws + WS_WVT);
        uint4 wv[12];
        #pragma unroll
        for (int mt = 0; mt < 12; ++mt) wv[mt] = WVT[mt * 64 + lane];
        float* vout = out + (size_t)NB * NE * 128;
        #pragma unroll
        for (int mt = 0; mt < 12; ++mt)
            #pragma unroll
            for (int nt = 0; nt < 2; ++nt) {
                f32x4 av = MF(wv[mt], vbv[nt], zero4);
                const size_t e = eg0 + ew0 + nt * 16 + lm;
                *(f32x4*)&vout[e * 192 + mt * 16 + la * 4] = av;
            }
        return;
    }

    // ================= a_out MLP =================
    float* s_normf = (float*)(smem + 6656);            // [6][128]
    uint4* s_W2 = (uint4*)(smem + 6656 + 3072);        // 2048 frags

    // stage W2 frag table into LDS (once per block; all waves cooperate)
    const uint4* W2T = (const uint4*)(ws + WS_W2T);
    {
        uint4 stg[8];
        #pragma unroll
        for (int it = 0; it < 8; ++it) stg[it] = W2T[it * 256 + tid];
        #pragma unroll
        for (int it = 0; it < 8; ++it) s_W2[it * 256 + tid] = stg[it];
    }

    // norms (wave-local)
    {
        float P[12];
        #pragma unroll
        for (int i = 0; i < 12; ++i) P[i] = s_pts[el][i];
        if (side == 0) {
            const int va[4] = {1, 3, 2, 3}, vbx[4] = {0, 2, 0, 1};
            #pragma unroll
            for (int i = 0; i < 4; ++i) {
                float x = P[va[i] * 3 + 0] - P[vbx[i] * 3 + 0];
                float y = P[va[i] * 3 + 1] - P[vbx[i] * 3 + 1];
                float z = P[va[i] * 3 + 2] - P[vbx[i] * 3 + 2];
                s_normf[i * 128 + el] = sqrtf(x * x + y * y + z * z);
            }
        } else {
            float x4 = P[6] - P[3], y4 = P[7] - P[4], z4 = P[8] - P[5];
            float x5 = P[9] - P[0], y5 = P[10] - P[1], z5 = P[11] - P[2];
            s_normf[4 * 128 + el] = sqrtf(x4 * x4 + y4 * y4 + z4 * z4);
            s_normf[5 * 128 + el] = sqrtf(x5 * x5 + y5 * y5 + z5 * z5);
        }
    }
    __syncthreads();   // staged W2 + all norms visible

    // --- layer 1 ---
    f32x4 acc[8][2];
    {
        uint4 vb1[2];
        #pragma unroll
        for (int nt = 0; nt < 2; ++nt) {
            const int e = ew0 + nt * 16 + lm;
            uint c0 = 0, c1 = 0;
            if (la == 0) {
                c0 = cvtpk(s_normf[0 * 128 + e], s_normf[1 * 128 + e]);
                c1 = cvtpk(s_normf[2 * 128 + e], s_normf[3 * 128 + e]);
            } else if (la == 1) {
                c0 = cvtpk(s_normf[4 * 128 + e], s_normf[5 * 128 + e]);
            }
            vb1[nt] = make_uint4(c0, c1, 0u, 0u);
        }
        const uint4* W1T = (const uint4*)(ws + WS_W1T);
        uint4 w1f[8];
        #pragma unroll
        for (int mt = 0; mt < 8; ++mt) w1f[mt] = W1T[mt * 64 + lane];
        #pragma unroll
        for (int mt = 0; mt < 8; ++mt)
            #pragma unroll
            for (int nt = 0; nt < 2; ++nt)
                acc[mt][nt] = MF(w1f[mt], vb1[nt], zero4);
    }
    uint4 vb[2][4];
    #pragma unroll
    for (int mt = 0; mt < 8; ++mt) {
        f32x4 bc = *(const f32x4*)&b1[mt * 16 + la * 4];
        #pragma unroll
        for (int nt = 0; nt < 2; ++nt)
            #pragma unroll
            for (int r = 0; r < 4; ++r) {
                float x = acc[mt][nt][r] + bc[r];
                acc[mt][nt][r] = fmaxf(x, 0.2f * x);
            }
    }
    #pragma unroll
    for (int nt = 0; nt < 2; ++nt)
        #pragma unroll
        for (int kt = 0; kt < 4; ++kt)
            vb[nt][kt] = make_uint4(
                cvtpk(acc[2*kt][nt][0], acc[2*kt][nt][1]),
                cvtpk(acc[2*kt][nt][2], acc[2*kt][nt][3]),
                cvtpk(acc[2*kt+1][nt][0], acc[2*kt+1][nt][1]),
                cvtpk(acc[2*kt+1][nt][2], acc[2*kt+1][nt][3]));

    // --- layer 2 (weights from LDS) ---
    #pragma unroll
    for (int mt = 0; mt < 8; ++mt)
        #pragma unroll
        for (int nt = 0; nt < 2; ++nt) acc[mt][nt] = zero4;
    #pragma unroll
    for (int kt = 0; kt < 4; ++kt) {
        uint4 wf[8];
        #pragma unroll
        for (int mt = 0; mt < 8; ++mt) wf[mt] = s_W2[(mt * 4 + kt) * 64 + lane];
        #pragma unroll
        for (int mt = 0; mt < 8; ++mt)
            #pragma unroll
            for (int nt = 0; nt < 2; ++nt)
                acc[mt][nt] = MF(wf[mt], vb[nt][kt], acc[mt][nt]);
    }
    #pragma unroll
    for (int mt = 0; mt < 8; ++mt) {
        f32x4 bc = *(const f32x4*)&b2[mt * 16 + la * 4];
        #pragma unroll
        for (int nt = 0; nt < 2; ++nt)
            #pragma unroll
            for (int r = 0; r < 4; ++r) {
                float x = acc[mt][nt][r] + bc[r];
                acc[mt][nt][r] = fmaxf(x, 0.2f * x);
            }
    }
    #pragma unroll
    for (int nt = 0; nt < 2; ++nt)
        #pragma unroll
        for (int kt = 0; kt < 4; ++kt)
            vb[nt][kt] = make_uint4(
                cvtpk(acc[2*kt][nt][0], acc[2*kt][nt][1]),
                cvtpk(acc[2*kt][nt][2], acc[2*kt][nt][3]),
                cvtpk(acc[2*kt+1][nt][0], acc[2*kt+1][nt][1]),
                cvtpk(acc[2*kt+1][nt][2], acc[2*kt+1][nt][3]));

    // --- layer 3 (weights from L2) ---
    const uint4* W3T = (const uint4*)(ws + WS_W3T);
    #pragma unroll
    for (int mt = 0; mt < 8; ++mt)
        #pragma unroll
        for (int nt = 0; nt < 2; ++nt) acc[mt][nt] = zero4;
    #pragma unroll
    for (int kt = 0; kt < 4; ++kt) {
        uint4 wf[8];
        #pragma unroll
        for (int mt = 0; mt < 8; ++mt) wf[mt] = W3T[(mt * 4 + kt) * 64 + lane];
        #pragma unroll
        for (int mt = 0; mt < 8; ++mt)
            #pragma unroll
            for (int nt = 0; nt < 2; ++nt)
                acc[mt][nt] = MF(wf[mt], vb[nt][kt], acc[mt][nt]);
    }
    // bias3 + direct a_out stores (full 64B chunks per edge per mt)
    #pragma unroll
    for (int mt = 0; mt < 8; ++mt) {
        f32x4 bc = *(const f32x4*)&b3[mt * 16 + la * 4];
        #pragma unroll
        for (int nt = 0; nt < 2; ++nt) {
            f32x4 v = acc[mt][nt] + bc;
            const size_t e = eg0 + ew0 + nt * 16 + lm;
            *(f32x4*)&out[e * 128 + mt * 16 + la * 4] = v;
        }
    }
}

extern "C" void kernel_launch(void* const* d_in, const int* in_sizes, int n_in,
                              void* d_out, int out_size, void* d_ws, size_t ws_size,
                              hipStream_t stream) {
    const float* pos0 = (const float*)d_in[0];
    const float* pos1 = (const float*)d_in[1];
    const int* src = (const int*)d_in[2];
    const int* dstI = (const int*)d_in[3];
    const float* Wv = (const float*)d_in[4];
    const float* W1 = (const float*)d_in[5];
    const float* b1 = (const float*)d_in[6];
    const float* W2 = (const float*)d_in[7];
    const float* b2 = (const float*)d_in[8];
    const float* W3 = (const float*)d_in[9];
    const float* b3 = (const float*)d_in[10];
    unsigned char* ws = (unsigned char*)d_ws;
    float* out = (float*)d_out;

    prep_kernel<<<dim3(21), dim3(256), 0, stream>>>(W1, W2, W3, Wv, ws);
    edge_kernel<<<dim3(NBLK), dim3(256), 0, stream>>>(pos0, pos1, src, dstI, b1, b2, b3, ws, out);
}